// Round 6
// baseline (527.348 us; speedup 1.0000x reference)
//
#include <hip/hip_runtime.h>
#include <hip/hip_bf16.h>

typedef __attribute__((ext_vector_type(8))) short short8;
typedef __attribute__((ext_vector_type(4))) ushort ushort4v;
typedef __attribute__((ext_vector_type(4))) float f32x4;

#define MFMA16(A, B, C) __builtin_amdgcn_mfma_f32_16x16x32_bf16(A, B, C, 0, 0, 0)

#define GLOAD16(gp, lp)                                        \
  __builtin_amdgcn_global_load_lds(                            \
      (__attribute__((address_space(1))) void*)(gp),           \
      (__attribute__((address_space(3))) void*)(lp), 16, 0, 0)

// Raw barrier/waitcnt (NOT __syncthreads: that drains vmcnt and reinstates
// the m97 ~20% barrier-drain ceiling). "memory" clobber pins all memory ops
// (ds_read/gload issues) on their side of each barrier.
#define SBAR()   asm volatile("s_barrier" ::: "memory")
#define LGKM0()  asm volatile("s_waitcnt lgkmcnt(0)" ::: "memory")
#define VMCNT6() asm volatile("s_waitcnt vmcnt(6)" ::: "memory")

static constexpr int Lx = 2048, Dx = 2048, Hx = 16, HDx = 128, NBx = 2;

__device__ __forceinline__ ushort f2bu(float f) {
  __hip_bfloat16 h = __float2bfloat16(f);
  union { __hip_bfloat16 h; ushort u; } v;
  v.h = h;
  return v.u;
}

__device__ __forceinline__ short8 pack8(const float4& a, const float4& b) {
  short8 r;
  r[0] = (short)f2bu(a.x); r[1] = (short)f2bu(a.y);
  r[2] = (short)f2bu(a.z); r[3] = (short)f2bu(a.w);
  r[4] = (short)f2bu(b.x); r[5] = (short)f2bu(b.y);
  r[6] = (short)f2bu(b.z); r[7] = (short)f2bu(b.w);
  return r;
}

// ---------------------------------------------------------------------------
// One-time f32 -> bf16 conversion of x and the 4 weight matrices.
// ---------------------------------------------------------------------------
__global__ void convert_kernel(const float* __restrict__ x,
                               const float* __restrict__ Wq,
                               const float* __restrict__ Wk,
                               const float* __restrict__ Wv,
                               const float* __restrict__ Wo,
                               ushort* __restrict__ xb, ushort* __restrict__ wqb,
                               ushort* __restrict__ wkb, ushort* __restrict__ wvb,
                               ushort* __restrict__ wob) {
  const int y = blockIdx.y;
  const float* s;
  ushort* d;
  int n;
  switch (y) {
    case 0: s = x;  d = xb;  n = NBx * Lx * Dx; break;
    case 1: s = Wq; d = wqb; n = Dx * Dx; break;
    case 2: s = Wk; d = wkb; n = Dx * Dx; break;
    case 3: s = Wv; d = wvb; n = Dx * Dx; break;
    default: s = Wo; d = wob; n = Dx * Dx; break;
  }
  const int stride = gridDim.x * blockDim.x * 8;
  for (int i = (blockIdx.x * blockDim.x + threadIdx.x) * 8; i < n; i += stride) {
    float4 a = *(const float4*)(s + i);
    float4 b = *(const float4*)(s + i + 4);
    *(short8*)(d + i) = pack8(a, b);
  }
}

// ---------------------------------------------------------------------------
// 256x256x(BK=64) 8-phase GEMM core (T3+T4+T5), K=2048 (NT=32 K-tiles).
// 512 threads = 8 waves (2M x 4N); per-wave output 128x64; acc[8][4] f32x4.
// LDS 128KB: per slot s (t&1), per matrix, two kk-half regions [256][32] bf16
// (64B rows -> ds_read_b128 at the 8-quad bank optimum; no swizzle needed).
// Phase kills exactly one region; stages target only dead regions:
//   q1: read A(kk0,m0-3)+B(kk0)      stage A-kk1(t+1)   [dead since (t-1).q4]
//   q2: read A(kk0,m4-7), reuse B    stage B-kk0(t+2)   [dead after t.q1]
//   q3: read A(kk1,m0-3)+B(kk1)      stage A-kk0(t+2)   [dead after t.q2]
//   q4: read A(kk1,m4-7), reuse B    stage B-kk1(t+2)   [dead after t.q3]
//        + vmcnt(6) once per tile (3 halves in flight; never drained to 0).
// ---------------------------------------------------------------------------
__device__ __forceinline__ void gemm256_core(const ushort* __restrict__ A0,
                                             const ushort* __restrict__ B0,
                                             f32x4 (&acc)[8][4], const int tid) {
  __shared__ ushort LA[2][2][8192];  // [slot][kk][row*32+c], 64KB
  __shared__ ushort LB[2][2][8192];  // 64KB

  const int lane = tid & 63;
  const int l15 = lane & 15, hi = (lane >> 4) & 3;
  const int w = tid >> 6, wr = w >> 2, wc = w & 3;
  constexpr int NT = 2048 / 64;

  // staging: region = 256 rows x 32 cols bf16; 2 gloads/thread (128 rows each);
  // LDS dest is wave-uniform base + lane*16B (linear) by construction.
  const ushort* aRow = A0 + (size_t)(tid >> 2) * Dx + (tid & 3) * 8;
  const ushort* bRow = B0 + (size_t)(tid >> 2) * Dx + (tid & 3) * 8;
  const int ldsT = (tid >> 2) * 32 + (tid & 3) * 8;

#define STG_A(s, kk, t)                                                     \
  do {                                                                      \
    GLOAD16(aRow + (t) * 64 + (kk) * 32, &LA[s][kk][ldsT]);                 \
    GLOAD16(aRow + (size_t)128 * Dx + (t) * 64 + (kk) * 32,                 \
            &LA[s][kk][4096 + ldsT]);                                       \
  } while (0)
#define STG_B(s, kk, t)                                                     \
  do {                                                                      \
    GLOAD16(bRow + (t) * 64 + (kk) * 32, &LB[s][kk][ldsT]);                 \
    GLOAD16(bRow + (size_t)128 * Dx + (t) * 64 + (kk) * 32,                 \
            &LB[s][kk][4096 + ldsT]);                                       \
  } while (0)

#pragma unroll
  for (int m = 0; m < 8; ++m)
#pragma unroll
    for (int n = 0; n < 4; ++n) acc[m][n] = {0.f, 0.f, 0.f, 0.f};

  // prologue: tile0 complete + 3 halves of tile1 (A-kk1(1) comes at t=0.q1)
  STG_B(0, 0, 0); STG_A(0, 0, 0); STG_B(0, 1, 0); STG_A(0, 1, 0);
  STG_B(1, 0, 1); STG_A(1, 0, 1); STG_B(1, 1, 1);
  VMCNT6();  // tile0's 8 loads landed; 6 (tile1) still in flight
  SBAR();

  const int ar0 = wr * 128 + l15;
  const int br0 = wc * 64 + l15;

  for (int t = 0; t < NT; ++t) {
    const int s = t & 1;
    short8 af[4], bf[4], ag[4];

    // ---- q1: kk0, m0-3 ----
#pragma unroll
    for (int m = 0; m < 4; ++m)
      af[m] = *(const short8*)&LA[s][0][(ar0 + m * 16) * 32 + hi * 8];
#pragma unroll
    for (int n = 0; n < 4; ++n)
      bf[n] = *(const short8*)&LB[s][0][(br0 + n * 16) * 32 + hi * 8];
    if (t + 1 < NT) STG_A(s ^ 1, 1, t + 1);
    SBAR(); LGKM0();
    __builtin_amdgcn_s_setprio(1);
#pragma unroll
    for (int m = 0; m < 4; ++m)
#pragma unroll
      for (int n = 0; n < 4; ++n) acc[m][n] = MFMA16(af[m], bf[n], acc[m][n]);
    __builtin_amdgcn_s_setprio(0);
    SBAR();

    // ---- q2: kk0, m4-7 (reuse bf) ----
#pragma unroll
    for (int m = 0; m < 4; ++m)
      ag[m] = *(const short8*)&LA[s][0][(ar0 + (m + 4) * 16) * 32 + hi * 8];
    if (t + 2 < NT) STG_B(s, 0, t + 2);
    SBAR(); LGKM0();
    __builtin_amdgcn_s_setprio(1);
#pragma unroll
    for (int m = 0; m < 4; ++m)
#pragma unroll
      for (int n = 0; n < 4; ++n)
        acc[m + 4][n] = MFMA16(ag[m], bf[n], acc[m + 4][n]);
    __builtin_amdgcn_s_setprio(0);
    SBAR();

    // ---- q3: kk1, m0-3 ----
#pragma unroll
    for (int m = 0; m < 4; ++m)
      af[m] = *(const short8*)&LA[s][1][(ar0 + m * 16) * 32 + hi * 8];
#pragma unroll
    for (int n = 0; n < 4; ++n)
      bf[n] = *(const short8*)&LB[s][1][(br0 + n * 16) * 32 + hi * 8];
    if (t + 2 < NT) STG_A(s, 0, t + 2);
    SBAR(); LGKM0();
    __builtin_amdgcn_s_setprio(1);
#pragma unroll
    for (int m = 0; m < 4; ++m)
#pragma unroll
      for (int n = 0; n < 4; ++n) acc[m][n] = MFMA16(af[m], bf[n], acc[m][n]);
    __builtin_amdgcn_s_setprio(0);
    SBAR();

    // ---- q4: kk1, m4-7 (reuse bf) ----
#pragma unroll
    for (int m = 0; m < 4; ++m)
      ag[m] = *(const short8*)&LA[s][1][(ar0 + (m + 4) * 16) * 32 + hi * 8];
    if (t + 2 < NT) STG_B(s, 1, t + 2);
    SBAR(); LGKM0();
    __builtin_amdgcn_s_setprio(1);
#pragma unroll
    for (int m = 0; m < 4; ++m)
#pragma unroll
      for (int n = 0; n < 4; ++n)
        acc[m + 4][n] = MFMA16(ag[m], bf[n], acc[m + 4][n]);
    __builtin_amdgcn_s_setprio(0);
    VMCNT6();  // tile t+1 fully landed before its q1 reads; never 0
    SBAR();
  }
#undef STG_A
#undef STG_B
}

// ---------------------------------------------------------------------------
// QKV projection: one 8-phase GEMM over concatenated [Wq;Wk;Wv] (6144x2048).
// grid (16, 24): blockIdx.y = z*8 + bn. Epilogue fuses bias+rotary+q-scale.
// ---------------------------------------------------------------------------
__global__ __launch_bounds__(512, 2) void qkv_kernel(
    const ushort* __restrict__ xb, const ushort* __restrict__ Wall,
    const float* __restrict__ bq, const float* __restrict__ bk,
    const float* __restrict__ bv,
    const float* __restrict__ sinT, const float* __restrict__ cosT,
    ushort* __restrict__ qw, ushort* __restrict__ kw, ushort* __restrict__ vw) {
  const int bm = blockIdx.x;   // 0..15
  const int bnp = blockIdx.y;  // 0..23
  const int z = bnp >> 3, bn = bnp & 7;
  const int tid = threadIdx.x;

  f32x4 acc[8][4];
  gemm256_core(xb + (size_t)bm * 256 * Dx, Wall + (size_t)bnp * 256 * Dx, acc, tid);

  const float* bias = (z == 0) ? bq : (z == 1) ? bk : bv;
  ushort* outp      = (z == 0) ? qw : (z == 1) ? kw : vw;
  const int lane = tid & 63, l15 = lane & 15, hi = (lane >> 4) & 3;
  const int w = tid >> 6, wr = w >> 2, wc = w & 3;
  const float rsHD = 0.08838834764831845f;  // 1/sqrt(128)
#pragma unroll
  for (int n = 0; n < 4; ++n) {
    const int nc = bn * 256 + wc * 64 + n * 16 + l15;  // 0..2047
    const int h = nc >> 7, d = nc & 127;
    const float bb = bias[nc];
#pragma unroll
    for (int m = 0; m < 8; ++m) {
#pragma unroll
      for (int r = 0; r < 4; ++r) {
        const int mg = bm * 256 + wr * 128 + m * 16 + hi * 4 + r;
        const int b = mg >> 11, l = mg & (Lx - 1);
        float v = acc[m][n][r] + bb;
        if (z < 2 && d < 64) v *= (cosT[l * 64 + d] - sinT[l * 64 + d]);
        if (z == 0) v *= rsHD;
        outp[(size_t)((b * Hx + h) * Lx + l) * HDx + d] = f2bu(v);
      }
    }
  }
}

// ---------------------------------------------------------------------------
// Output projection: same 8-phase core; f32 out + bias. grid (16, 8).
// ---------------------------------------------------------------------------
__global__ __launch_bounds__(512, 2) void oproj_kernel(
    const ushort* __restrict__ ctx, const ushort* __restrict__ wob,
    const float* __restrict__ bo, float* __restrict__ out) {
  const int bm = blockIdx.x;  // 0..15
  const int bn = blockIdx.y;  // 0..7
  const int tid = threadIdx.x;

  f32x4 acc[8][4];
  gemm256_core(ctx + (size_t)bm * 256 * Dx, wob + (size_t)bn * 256 * Dx, acc, tid);

  const int lane = tid & 63, l15 = lane & 15, hi = (lane >> 4) & 3;
  const int w = tid >> 6, wr = w >> 2, wc = w & 3;
#pragma unroll
  for (int n = 0; n < 4; ++n) {
    const int nc = bn * 256 + wc * 64 + n * 16 + l15;
    const float bb = bo[nc];
#pragma unroll
    for (int m = 0; m < 8; ++m) {
#pragma unroll
      for (int r = 0; r < 4; ++r) {
        const int mg = bm * 256 + wr * 128 + m * 16 + hi * 4 + r;
        out[(size_t)mg * Dx + nc] = acc[m][n][r] + bb;
      }
    }
  }
}

// ---------------------------------------------------------------------------
// Causal flash attention (unchanged from R5): pair-balanced grid, T14
// async-STAGE, padded Ps/Vt, setprio.
// ---------------------------------------------------------------------------
__global__ __launch_bounds__(256, 2) void attn_kernel(
    const ushort* __restrict__ qw, const ushort* __restrict__ kw,
    const ushort* __restrict__ vw, ushort* __restrict__ ctx) {
  const int pair = blockIdx.x;  // 0..15
  const int bh = blockIdx.y;
  const int b = bh >> 4, h = bh & 15;
  const int tid = threadIdx.x;
  const int w = tid >> 6, l15 = tid & 15, hi = (tid >> 4) & 3;

  const ushort* Q = qw + (size_t)bh * Lx * HDx;
  const ushort* K = kw + (size_t)bh * Lx * HDx;
  const ushort* V = vw + (size_t)bh * Lx * HDx;

  __shared__ ushort Ks[64][136];
  __shared__ ushort Vt[128][76];
  __shared__ ushort Ps[4][16][76];

  const int skrow = tid >> 2, skd = (tid & 3) * 32;
  const int svk = (tid & 15) * 4, svd = (tid >> 4) * 8;

  for (int seg = 0; seg < 2; ++seg) {
    const int qt = seg ? (31 - pair) : pair;

    short8 qf[4];
    {
      const ushort* qr = Q + (size_t)(qt * 64 + w * 16 + l15) * HDx + hi * 8;
#pragma unroll
      for (int ds = 0; ds < 4; ++ds) qf[ds] = *(const short8*)(qr + ds * 32);
    }

    f32x4 o[8];
#pragma unroll
    for (int df = 0; df < 8; ++df) o[df] = {0.f, 0.f, 0.f, 0.f};
    float mr[4], lr[4];
#pragma unroll
    for (int r = 0; r < 4; ++r) { mr[r] = -1e30f; lr[r] = 0.f; }

    short8 kreg[4], vreg[4];
    {
      const ushort* kp = K + (size_t)skrow * HDx + skd;
      kreg[0] = *(const short8*)(kp + 0);  kreg[1] = *(const short8*)(kp + 8);
      kreg[2] = *(const short8*)(kp + 16); kreg[3] = *(const short8*)(kp + 24);
      const ushort* vp = V + (size_t)svk * HDx + svd;
      vreg[0] = *(const short8*)(vp);
      vreg[1] = *(const short8*)(vp + HDx);
      vreg[2] = *(const short8*)(vp + 2 * HDx);
      vreg[3] = *(const short8*)(vp + 3 * HDx);
    }

    for (int kv = 0; kv <= qt; ++kv) {
      __syncthreads();
      *(short8*)&Ks[skrow][skd + 0] = kreg[0];
      *(short8*)&Ks[skrow][skd + 8] = kreg[1];
      *(short8*)&Ks[skrow][skd + 16] = kreg[2];
      *(short8*)&Ks[skrow][skd + 24] = kreg[3];
#pragma unroll
      for (int j = 0; j < 8; ++j) {
        ushort4v pk;
        pk[0] = (ushort)vreg[0][j]; pk[1] = (ushort)vreg[1][j];
        pk[2] = (ushort)vreg[2][j]; pk[3] = (ushort)vreg[3][j];
        *(ushort4v*)&Vt[svd + j][svk] = pk;
      }
      __syncthreads();

      if (kv < qt) {
        const ushort* kp = K + (size_t)((kv + 1) * 64 + skrow) * HDx + skd;
        kreg[0] = *(const short8*)(kp + 0);  kreg[1] = *(const short8*)(kp + 8);
        kreg[2] = *(const short8*)(kp + 16); kreg[3] = *(const short8*)(kp + 24);
        const ushort* vp = V + (size_t)((kv + 1) * 64 + svk) * HDx + svd;
        vreg[0] = *(const short8*)(vp);
        vreg[1] = *(const short8*)(vp + HDx);
        vreg[2] = *(const short8*)(vp + 2 * HDx);
        vreg[3] = *(const short8*)(vp + 3 * HDx);
      }

      f32x4 s[4];
#pragma unroll
      for (int kf = 0; kf < 4; ++kf) s[kf] = {0.f, 0.f, 0.f, 0.f};
      __builtin_amdgcn_s_setprio(1);
#pragma unroll
      for (int kf = 0; kf < 4; ++kf)
#pragma unroll
        for (int ds = 0; ds < 4; ++ds) {
          short8 kb = *(const short8*)&Ks[kf * 16 + l15][ds * 32 + hi * 8];
          s[kf] = MFMA16(qf[ds], kb, s[kf]);
        }
      __builtin_amdgcn_s_setprio(0);

      if (kv == qt) {
#pragma unroll
        for (int kf = 0; kf < 4; ++kf)
#pragma unroll
          for (int r = 0; r < 4; ++r)
            if (kf * 16 + l15 > w * 16 + hi * 4 + r) s[kf][r] = -1e30f;
      }

      float ml[4];
#pragma unroll
      for (int r = 0; r < 4; ++r)
        ml[r] = fmaxf(fmaxf(s[0][r], s[1][r]), fmaxf(s[2][r], s[3][r]));
#pragma unroll
      for (int off = 1; off <= 8; off <<= 1)
#pragma unroll
        for (int r = 0; r < 4; ++r) ml[r] = fmaxf(ml[r], __shfl_xor(ml[r], off));
      float scl[4];
#pragma unroll
      for (int r = 0; r < 4; ++r) {
        float mn = fmaxf(mr[r], ml[r]);
        scl[r] = __expf(mr[r] - mn);
        mr[r] = mn;
      }
      float ll[4] = {0.f, 0.f, 0.f, 0.f};
#pragma unroll
      for (int kf = 0; kf < 4; ++kf)
#pragma unroll
        for (int r = 0; r < 4; ++r) {
          float p = __expf(s[kf][r] - mr[r]);
          s[kf][r] = p;
          ll[r] += p;
        }
#pragma unroll
      for (int off = 1; off <= 8; off <<= 1)
#pragma unroll
        for (int r = 0; r < 4; ++r) ll[r] += __shfl_xor(ll[r], off);
#pragma unroll
      for (int r = 0; r < 4; ++r) lr[r] = lr[r] * scl[r] + ll[r];
#pragma unroll
      for (int df = 0; df < 8; ++df)
#pragma unroll
        for (int r = 0; r < 4; ++r) o[df][r] *= scl[r];

#pragma unroll
      for (int kf = 0; kf < 4; ++kf)
#pragma unroll
        for (int r = 0; r < 4; ++r)
          Ps[w][hi * 4 + r][kf * 16 + l15] = f2bu(s[kf][r]);

      short8 pa0 = *(const short8*)&Ps[w][l15][hi * 8];
      short8 pa1 = *(const short8*)&Ps[w][l15][32 + hi * 8];
      __builtin_amdgcn_s_setprio(1);
#pragma unroll
      for (int df = 0; df < 8; ++df) {
        short8 v0 = *(const short8*)&Vt[df * 16 + l15][hi * 8];
        short8 v1 = *(const short8*)&Vt[df * 16 + l15][32 + hi * 8];
        o[df] = MFMA16(pa0, v0, o[df]);
        o[df] = MFMA16(pa1, v1, o[df]);
      }
      __builtin_amdgcn_s_setprio(0);
    }

    float inv[4];
#pragma unroll
    for (int r = 0; r < 4; ++r) inv[r] = 1.0f / lr[r];
    ushort* cp = ctx + (size_t)(b * Lx + qt * 64 + w * 16) * Dx + h * HDx;
#pragma unroll
    for (int df = 0; df < 8; ++df)
#pragma unroll
      for (int r = 0; r < 4; ++r)
        cp[(size_t)(hi * 4 + r) * Dx + df * 16 + l15] = f2bu(o[df][r] * inv[r]);
  }
}

extern "C" void kernel_launch(void* const* d_in, const int* in_sizes, int n_in,
                              void* d_out, int out_size, void* d_ws, size_t ws_size,
                              hipStream_t stream) {
  (void)in_sizes; (void)n_in; (void)out_size; (void)ws_size;
  const float* x    = (const float*)d_in[0];
  const float* sinT = (const float*)d_in[1];
  const float* cosT = (const float*)d_in[2];
  // d_in[3] = mask (causal tril) — enforced analytically in attn_kernel
  const float* Wq = (const float*)d_in[4];
  const float* bq = (const float*)d_in[5];
  const float* Wk = (const float*)d_in[6];
  const float* bk = (const float*)d_in[7];
  const float* Wv = (const float*)d_in[8];
  const float* bv = (const float*)d_in[9];
  const float* Wo = (const float*)d_in[10];
  const float* bo = (const float*)d_in[11];
  float* out = (float*)d_out;

  const size_t N = (size_t)NBx * Lx * Dx;  // 8,388,608
  const size_t M = (size_t)Dx * Dx;        // 4,194,304
  ushort* qw  = (ushort*)d_ws;
  ushort* kw  = qw + N;
  ushort* vw  = kw + N;
  ushort* ctx = vw + N;
  ushort* xb  = ctx;  // alias: xb consumed by qkv before attn writes ctx
  ushort* wqb = ctx + N;  // wqb/wkb/wvb contiguous -> [Wq;Wk;Wv] (6144x2048)
  ushort* wkb = wqb + M;
  ushort* wvb = wkb + M;
  ushort* wob = wvb + M;
  (void)wkb; (void)wvb;

  convert_kernel<<<dim3(1024, 5), 256, 0, stream>>>(
      x, Wq, Wk, Wv, Wo, xb, wqb, wkb, wvb, wob);
  qkv_kernel<<<dim3(16, 24), 512, 0, stream>>>(
      xb, wqb, bq, bk, bv, sinT, cosT, qw, kw, vw);
  attn_kernel<<<dim3(16, 32), 256, 0, stream>>>(qw, kw, vw, ctx);
  oproj_kernel<<<dim3(16, 8), 512, 0, stream>>>(ctx, wob, bo, out);
}

// Round 8
// 509.608 us; speedup vs baseline: 1.0348x; 1.0348x over previous
//
#include <hip/hip_runtime.h>
#include <hip/hip_bf16.h>

typedef __attribute__((ext_vector_type(8))) short short8;
typedef __attribute__((ext_vector_type(4))) ushort ushort4v;
typedef __attribute__((ext_vector_type(4))) float f32x4;

#define MFMA16(A, B, C) __builtin_amdgcn_mfma_f32_16x16x32_bf16(A, B, C, 0, 0, 0)

#define GLOAD16(gp, lp)                                        \
  __builtin_amdgcn_global_load_lds(                            \
      (__attribute__((address_space(1))) void*)(gp),           \
      (__attribute__((address_space(3))) void*)(lp), 16, 0, 0)

// Raw barrier/waitcnt (NOT __syncthreads: that drains vmcnt and reinstates
// the m97 ~20% barrier-drain ceiling).
#define SBAR()   asm volatile("s_barrier" ::: "memory")
#define LGKM0()  asm volatile("s_waitcnt lgkmcnt(0)" ::: "memory")
#define VMCNT6() asm volatile("s_waitcnt vmcnt(6)" ::: "memory")

static constexpr int Lx = 2048, Dx = 2048, Hx = 16, HDx = 128, NBx = 2;

__device__ __forceinline__ ushort f2bu(float f) {
  __hip_bfloat16 h = __float2bfloat16(f);
  union { __hip_bfloat16 h; ushort u; } v;
  v.h = h;
  return v.u;
}

__device__ __forceinline__ short8 pack8(const float4& a, const float4& b) {
  short8 r;
  r[0] = (short)f2bu(a.x); r[1] = (short)f2bu(a.y);
  r[2] = (short)f2bu(a.z); r[3] = (short)f2bu(a.w);
  r[4] = (short)f2bu(b.x); r[5] = (short)f2bu(b.y);
  r[6] = (short)f2bu(b.z); r[7] = (short)f2bu(b.w);
  return r;
}

// ---------------------------------------------------------------------------
// One-time f32 -> bf16 conversion of x and the 4 weight matrices.
// ---------------------------------------------------------------------------
__global__ void convert_kernel(const float* __restrict__ x,
                               const float* __restrict__ Wq,
                               const float* __restrict__ Wk,
                               const float* __restrict__ Wv,
                               const float* __restrict__ Wo,
                               ushort* __restrict__ xb, ushort* __restrict__ wqb,
                               ushort* __restrict__ wkb, ushort* __restrict__ wvb,
                               ushort* __restrict__ wob) {
  const int y = blockIdx.y;
  const float* s;
  ushort* d;
  int n;
  switch (y) {
    case 0: s = x;  d = xb;  n = NBx * Lx * Dx; break;
    case 1: s = Wq; d = wqb; n = Dx * Dx; break;
    case 2: s = Wk; d = wkb; n = Dx * Dx; break;
    case 3: s = Wv; d = wvb; n = Dx * Dx; break;
    default: s = Wo; d = wob; n = Dx * Dx; break;
  }
  const int stride = gridDim.x * blockDim.x * 8;
  for (int i = (blockIdx.x * blockDim.x + threadIdx.x) * 8; i < n; i += stride) {
    float4 a = *(const float4*)(s + i);
    float4 b = *(const float4*)(s + i + 4);
    *(short8*)(d + i) = pack8(a, b);
  }
}

// ---------------------------------------------------------------------------
// 256x256x(BK=64) 8-phase GEMM core (T2+T3+T4+T5), K=2048 (NT=32 K-tiles).
// T2 XOR-swizzle slot' = slot ^ ((row>>1)&3) on each [256][32] region
// (rule #21: linear LDS dest for global_load_lds + inverse-swizzled GLOBAL
// source column + swizzled READ; involution). Unswizzled, the 16-row
// fragment sweep at fixed 16B slot was an 8-way bank conflict; swizzled,
// each of 8 bank-groups gets exactly 2 lanes -> free (m136). f(row)
// collapses to per-lane constants on both sides -> zero extra VALU.
// ---------------------------------------------------------------------------
__device__ __forceinline__ void gemm256_core(const ushort* __restrict__ A0,
                                             const ushort* __restrict__ B0,
                                             f32x4 (&acc)[8][4], const int tid) {
  __shared__ ushort LA[2][2][8192];  // [slot][kk][row*32+col], 64KB
  __shared__ ushort LB[2][2][8192];  // 64KB

  const int lane = tid & 63;
  const int l15 = lane & 15, hi = (lane >> 4) & 3;
  const int w = tid >> 6, wr = w >> 2, wc = w & 3;
  constexpr int NT = 2048 / 64;

  // swizzled read slot offset (elems): per-lane constant
  const int hs = (hi ^ ((l15 >> 1) & 3)) * 8;

  // staging: thread t -> LDS row tid>>2 (+128 for 2nd gload), slot tid&3;
  // source column is the INVERSE-swizzled slot so swizzled data lands at
  // the linear dest global_load_lds requires.
  const int srcSlot = ((tid & 3) ^ ((tid >> 3) & 3)) * 8;
  const ushort* aRow = A0 + (size_t)(tid >> 2) * Dx + srcSlot;
  const ushort* bRow = B0 + (size_t)(tid >> 2) * Dx + srcSlot;
  const int ldsT = (tid >> 2) * 32 + (tid & 3) * 8;  // linear: tid*16 bytes

#define STG_A(s, kk, t)                                                     \
  do {                                                                      \
    GLOAD16(aRow + (t) * 64 + (kk) * 32, &LA[s][kk][ldsT]);                 \
    GLOAD16(aRow + (size_t)128 * Dx + (t) * 64 + (kk) * 32,                 \
            &LA[s][kk][4096 + ldsT]);                                       \
  } while (0)
#define STG_B(s, kk, t)                                                     \
  do {                                                                      \
    GLOAD16(bRow + (t) * 64 + (kk) * 32, &LB[s][kk][ldsT]);                 \
    GLOAD16(bRow + (size_t)128 * Dx + (t) * 64 + (kk) * 32,                 \
            &LB[s][kk][4096 + ldsT]);                                       \
  } while (0)

#pragma unroll
  for (int m = 0; m < 8; ++m)
#pragma unroll
    for (int n = 0; n < 4; ++n) acc[m][n] = {0.f, 0.f, 0.f, 0.f};

  // prologue: tile0 complete + 3 halves of tile1 (A-kk1(1) comes at t=0.q1)
  STG_B(0, 0, 0); STG_A(0, 0, 0); STG_B(0, 1, 0); STG_A(0, 1, 0);
  STG_B(1, 0, 1); STG_A(1, 0, 1); STG_B(1, 1, 1);
  VMCNT6();  // tile0's 8 loads landed; 6 (tile1) still in flight
  SBAR();

  const int ar0 = wr * 128 + l15;
  const int br0 = wc * 64 + l15;

  for (int t = 0; t < NT; ++t) {
    const int s = t & 1;
    short8 af[4], bf[4], ag[4];

    // ---- q1: kk0, m0-3 ----
#pragma unroll
    for (int m = 0; m < 4; ++m)
      af[m] = *(const short8*)&LA[s][0][(ar0 + m * 16) * 32 + hs];
#pragma unroll
    for (int n = 0; n < 4; ++n)
      bf[n] = *(const short8*)&LB[s][0][(br0 + n * 16) * 32 + hs];
    if (t + 1 < NT) STG_A(s ^ 1, 1, t + 1);
    SBAR(); LGKM0();
    __builtin_amdgcn_s_setprio(1);
#pragma unroll
    for (int m = 0; m < 4; ++m)
#pragma unroll
      for (int n = 0; n < 4; ++n) acc[m][n] = MFMA16(af[m], bf[n], acc[m][n]);
    __builtin_amdgcn_s_setprio(0);
    SBAR();

    // ---- q2: kk0, m4-7 (reuse bf) ----
#pragma unroll
    for (int m = 0; m < 4; ++m)
      ag[m] = *(const short8*)&LA[s][0][(ar0 + (m + 4) * 16) * 32 + hs];
    if (t + 2 < NT) STG_B(s, 0, t + 2);
    SBAR(); LGKM0();
    __builtin_amdgcn_s_setprio(1);
#pragma unroll
    for (int m = 0; m < 4; ++m)
#pragma unroll
      for (int n = 0; n < 4; ++n)
        acc[m + 4][n] = MFMA16(ag[m], bf[n], acc[m + 4][n]);
    __builtin_amdgcn_s_setprio(0);
    SBAR();

    // ---- q3: kk1, m0-3 ----
#pragma unroll
    for (int m = 0; m < 4; ++m)
      af[m] = *(const short8*)&LA[s][1][(ar0 + m * 16) * 32 + hs];
#pragma unroll
    for (int n = 0; n < 4; ++n)
      bf[n] = *(const short8*)&LB[s][1][(br0 + n * 16) * 32 + hs];
    if (t + 2 < NT) STG_A(s, 0, t + 2);
    SBAR(); LGKM0();
    __builtin_amdgcn_s_setprio(1);
#pragma unroll
    for (int m = 0; m < 4; ++m)
#pragma unroll
      for (int n = 0; n < 4; ++n) acc[m][n] = MFMA16(af[m], bf[n], acc[m][n]);
    __builtin_amdgcn_s_setprio(0);
    SBAR();

    // ---- q4: kk1, m4-7 (reuse bf) ----
#pragma unroll
    for (int m = 0; m < 4; ++m)
      ag[m] = *(const short8*)&LA[s][1][(ar0 + (m + 4) * 16) * 32 + hs];
    if (t + 2 < NT) STG_B(s, 1, t + 2);
    SBAR(); LGKM0();
    __builtin_amdgcn_s_setprio(1);
#pragma unroll
    for (int m = 0; m < 4; ++m)
#pragma unroll
      for (int n = 0; n < 4; ++n)
        acc[m + 4][n] = MFMA16(ag[m], bf[n], acc[m + 4][n]);
    __builtin_amdgcn_s_setprio(0);
    VMCNT6();  // tile t+1 fully landed before its q1 reads; never 0
    SBAR();
  }
#undef STG_A
#undef STG_B
}

// ---------------------------------------------------------------------------
// QKV projection: one 8-phase GEMM over concatenated [Wq;Wk;Wv] (6144x2048).
// ---------------------------------------------------------------------------
__global__ __launch_bounds__(512, 2) void qkv_kernel(
    const ushort* __restrict__ xb, const ushort* __restrict__ Wall,
    const float* __restrict__ bq, const float* __restrict__ bk,
    const float* __restrict__ bv,
    const float* __restrict__ sinT, const float* __restrict__ cosT,
    ushort* __restrict__ qw, ushort* __restrict__ kw, ushort* __restrict__ vw) {
  const int bm = blockIdx.x;   // 0..15
  const int bnp = blockIdx.y;  // 0..23
  const int z = bnp >> 3, bn = bnp & 7;
  const int tid = threadIdx.x;

  f32x4 acc[8][4];
  gemm256_core(xb + (size_t)bm * 256 * Dx, Wall + (size_t)bnp * 256 * Dx, acc, tid);

  const float* bias = (z == 0) ? bq : (z == 1) ? bk : bv;
  ushort* outp      = (z == 0) ? qw : (z == 1) ? kw : vw;
  const int lane = tid & 63, l15 = lane & 15, hi = (lane >> 4) & 3;
  const int w = tid >> 6, wr = w >> 2, wc = w & 3;
  const float rsHD = 0.08838834764831845f;  // 1/sqrt(128)
#pragma unroll
  for (int n = 0; n < 4; ++n) {
    const int nc = bn * 256 + wc * 64 + n * 16 + l15;  // 0..2047
    const int h = nc >> 7, d = nc & 127;
    const float bb = bias[nc];
#pragma unroll
    for (int m = 0; m < 8; ++m) {
#pragma unroll
      for (int r = 0; r < 4; ++r) {
        const int mg = bm * 256 + wr * 128 + m * 16 + hi * 4 + r;
        const int b = mg >> 11, l = mg & (Lx - 1);
        float v = acc[m][n][r] + bb;
        if (z < 2 && d < 64) v *= (cosT[l * 64 + d] - sinT[l * 64 + d]);
        if (z == 0) v *= rsHD;
        outp[(size_t)((b * Hx + h) * Lx + l) * HDx + d] = f2bu(v);
      }
    }
  }
}

// ---------------------------------------------------------------------------
// Output projection: same 8-phase core; f32 out + bias. grid (16, 8).
// ---------------------------------------------------------------------------
__global__ __launch_bounds__(512, 2) void oproj_kernel(
    const ushort* __restrict__ ctx, const ushort* __restrict__ wob,
    const float* __restrict__ bo, float* __restrict__ out) {
  const int bm = blockIdx.x;  // 0..15
  const int bn = blockIdx.y;  // 0..7
  const int tid = threadIdx.x;

  f32x4 acc[8][4];
  gemm256_core(ctx + (size_t)bm * 256 * Dx, wob + (size_t)bn * 256 * Dx, acc, tid);

  const int lane = tid & 63, l15 = lane & 15, hi = (lane >> 4) & 3;
  const int w = tid >> 6, wr = w >> 2, wc = w & 3;
#pragma unroll
  for (int n = 0; n < 4; ++n) {
    const int nc = bn * 256 + wc * 64 + n * 16 + l15;
    const float bb = bo[nc];
#pragma unroll
    for (int m = 0; m < 8; ++m) {
#pragma unroll
      for (int r = 0; r < 4; ++r) {
        const int mg = bm * 256 + wr * 128 + m * 16 + hi * 4 + r;
        out[(size_t)mg * Dx + nc] = acc[m][n][r] + bb;
      }
    }
  }
}

// ---------------------------------------------------------------------------
// Causal flash attention (unchanged from R5/R6).
// ---------------------------------------------------------------------------
__global__ __launch_bounds__(256, 2) void attn_kernel(
    const ushort* __restrict__ qw, const ushort* __restrict__ kw,
    const ushort* __restrict__ vw, ushort* __restrict__ ctx) {
  const int pair = blockIdx.x;  // 0..15
  const int bh = blockIdx.y;
  const int b = bh >> 4, h = bh & 15;
  const int tid = threadIdx.x;
  const int w = tid >> 6, l15 = tid & 15, hi = (tid >> 4) & 3;

  const ushort* Q = qw + (size_t)bh * Lx * HDx;
  const ushort* K = kw + (size_t)bh * Lx * HDx;
  const ushort* V = vw + (size_t)bh * Lx * HDx;

  __shared__ ushort Ks[64][136];
  __shared__ ushort Vt[128][76];
  __shared__ ushort Ps[4][16][76];

  const int skrow = tid >> 2, skd = (tid & 3) * 32;
  const int svk = (tid & 15) * 4, svd = (tid >> 4) * 8;

  for (int seg = 0; seg < 2; ++seg) {
    const int qt = seg ? (31 - pair) : pair;

    short8 qf[4];
    {
      const ushort* qr = Q + (size_t)(qt * 64 + w * 16 + l15) * HDx + hi * 8;
#pragma unroll
      for (int ds = 0; ds < 4; ++ds) qf[ds] = *(const short8*)(qr + ds * 32);
    }

    f32x4 o[8];
#pragma unroll
    for (int df = 0; df < 8; ++df) o[df] = {0.f, 0.f, 0.f, 0.f};
    float mr[4], lr[4];
#pragma unroll
    for (int r = 0; r < 4; ++r) { mr[r] = -1e30f; lr[r] = 0.f; }

    short8 kreg[4], vreg[4];
    {
      const ushort* kp = K + (size_t)skrow * HDx + skd;
      kreg[0] = *(const short8*)(kp + 0);  kreg[1] = *(const short8*)(kp + 8);
      kreg[2] = *(const short8*)(kp + 16); kreg[3] = *(const short8*)(kp + 24);
      const ushort* vp = V + (size_t)svk * HDx + svd;
      vreg[0] = *(const short8*)(vp);
      vreg[1] = *(const short8*)(vp + HDx);
      vreg[2] = *(const short8*)(vp + 2 * HDx);
      vreg[3] = *(const short8*)(vp + 3 * HDx);
    }

    for (int kv = 0; kv <= qt; ++kv) {
      __syncthreads();
      *(short8*)&Ks[skrow][skd + 0] = kreg[0];
      *(short8*)&Ks[skrow][skd + 8] = kreg[1];
      *(short8*)&Ks[skrow][skd + 16] = kreg[2];
      *(short8*)&Ks[skrow][skd + 24] = kreg[3];
#pragma unroll
      for (int j = 0; j < 8; ++j) {
        ushort4v pk;
        pk[0] = (ushort)vreg[0][j]; pk[1] = (ushort)vreg[1][j];
        pk[2] = (ushort)vreg[2][j]; pk[3] = (ushort)vreg[3][j];
        *(ushort4v*)&Vt[svd + j][svk] = pk;
      }
      __syncthreads();

      if (kv < qt) {
        const ushort* kp = K + (size_t)((kv + 1) * 64 + skrow) * HDx + skd;
        kreg[0] = *(const short8*)(kp + 0);  kreg[1] = *(const short8*)(kp + 8);
        kreg[2] = *(const short8*)(kp + 16); kreg[3] = *(const short8*)(kp + 24);
        const ushort* vp = V + (size_t)((kv + 1) * 64 + svk) * HDx + svd;
        vreg[0] = *(const short8*)(vp);
        vreg[1] = *(const short8*)(vp + HDx);
        vreg[2] = *(const short8*)(vp + 2 * HDx);
        vreg[3] = *(const short8*)(vp + 3 * HDx);
      }

      f32x4 s[4];
#pragma unroll
      for (int kf = 0; kf < 4; ++kf) s[kf] = {0.f, 0.f, 0.f, 0.f};
      __builtin_amdgcn_s_setprio(1);
#pragma unroll
      for (int kf = 0; kf < 4; ++kf)
#pragma unroll
        for (int ds = 0; ds < 4; ++ds) {
          short8 kb = *(const short8*)&Ks[kf * 16 + l15][ds * 32 + hi * 8];
          s[kf] = MFMA16(qf[ds], kb, s[kf]);
        }
      __builtin_amdgcn_s_setprio(0);

      if (kv == qt) {
#pragma unroll
        for (int kf = 0; kf < 4; ++kf)
#pragma unroll
          for (int r = 0; r < 4; ++r)
            if (kf * 16 + l15 > w * 16 + hi * 4 + r) s[kf][r] = -1e30f;
      }

      float ml[4];
#pragma unroll
      for (int r = 0; r < 4; ++r)
        ml[r] = fmaxf(fmaxf(s[0][r], s[1][r]), fmaxf(s[2][r], s[3][r]));
#pragma unroll
      for (int off = 1; off <= 8; off <<= 1)
#pragma unroll
        for (int r = 0; r < 4; ++r) ml[r] = fmaxf(ml[r], __shfl_xor(ml[r], off));
      float scl[4];
#pragma unroll
      for (int r = 0; r < 4; ++r) {
        float mn = fmaxf(mr[r], ml[r]);
        scl[r] = __expf(mr[r] - mn);
        mr[r] = mn;
      }
      float ll[4] = {0.f, 0.f, 0.f, 0.f};
#pragma unroll
      for (int kf = 0; kf < 4; ++kf)
#pragma unroll
        for (int r = 0; r < 4; ++r) {
          float p = __expf(s[kf][r] - mr[r]);
          s[kf][r] = p;
          ll[r] += p;
        }
#pragma unroll
      for (int off = 1; off <= 8; off <<= 1)
#pragma unroll
        for (int r = 0; r < 4; ++r) ll[r] += __shfl_xor(ll[r], off);
#pragma unroll
      for (int r = 0; r < 4; ++r) lr[r] = lr[r] * scl[r] + ll[r];
#pragma unroll
      for (int df = 0; df < 8; ++df)
#pragma unroll
        for (int r = 0; r < 4; ++r) o[df][r] *= scl[r];

#pragma unroll
      for (int kf = 0; kf < 4; ++kf)
#pragma unroll
        for (int r = 0; r < 4; ++r)
          Ps[w][hi * 4 + r][kf * 16 + l15] = f2bu(s[kf][r]);

      short8 pa0 = *(const short8*)&Ps[w][l15][hi * 8];
      short8 pa1 = *(const short8*)&Ps[w][l15][32 + hi * 8];
      __builtin_amdgcn_s_setprio(1);
#pragma unroll
      for (int df = 0; df < 8; ++df) {
        short8 v0 = *(const short8*)&Vt[df * 16 + l15][hi * 8];
        short8 v1 = *(const short8*)&Vt[df * 16 + l15][32 + hi * 8];
        o[df] = MFMA16(pa0, v0, o[df]);
        o[df] = MFMA16(pa1, v1, o[df]);
      }
      __builtin_amdgcn_s_setprio(0);
    }

    float inv[4];
#pragma unroll
    for (int r = 0; r < 4; ++r) inv[r] = 1.0f / lr[r];
    ushort* cp = ctx + (size_t)(b * Lx + qt * 64 + w * 16) * Dx + h * HDx;
#pragma unroll
    for (int df = 0; df < 8; ++df)
#pragma unroll
      for (int r = 0; r < 4; ++r)
        cp[(size_t)(hi * 4 + r) * Dx + df * 16 + l15] = f2bu(o[df][r] * inv[r]);
  }
}

extern "C" void kernel_launch(void* const* d_in, const int* in_sizes, int n_in,
                              void* d_out, int out_size, void* d_ws, size_t ws_size,
                              hipStream_t stream) {
  (void)in_sizes; (void)n_in; (void)out_size; (void)ws_size;
  const float* x    = (const float*)d_in[0];
  const float* sinT = (const float*)d_in[1];
  const float* cosT = (const float*)d_in[2];
  // d_in[3] = mask (causal tril) — enforced analytically in attn_kernel
  const float* Wq = (const float*)d_in[4];
  const float* bq = (const float*)d_in[5];
  const float* Wk = (const float*)d_in[6];
  const float* bk = (const float*)d_in[7];
  const float* Wv = (const float*)d_in[8];
  const float* bv = (const float*)d_in[9];
  const float* Wo = (const float*)d_in[10];
  const float* bo = (const float*)d_in[11];
  float* out = (float*)d_out;

  const size_t N = (size_t)NBx * Lx * Dx;  // 8,388,608
  const size_t M = (size_t)Dx * Dx;        // 4,194,304
  ushort* qw  = (ushort*)d_ws;
  ushort* kw  = qw + N;
  ushort* vw  = kw + N;
  ushort* ctx = vw + N;
  ushort* xb  = ctx;  // alias: xb consumed by qkv before attn writes ctx
  ushort* wqb = ctx + N;  // wqb/wkb/wvb contiguous -> [Wq;Wk;Wv] (6144x2048)
  ushort* wkb = wqb + M;
  ushort* wvb = wkb + M;
  ushort* wob = wvb + M;
  (void)wkb; (void)wvb;

  convert_kernel<<<dim3(1024, 5), 256, 0, stream>>>(
      x, Wq, Wk, Wv, Wo, xb, wqb, wkb, wvb, wob);
  qkv_kernel<<<dim3(16, 24), 512, 0, stream>>>(
      xb, wqb, bq, bk, bv, sinT, cosT, qw, kw, vw);
  attn_kernel<<<dim3(16, 32), 256, 0, stream>>>(qw, kw, vw, ctx);
  oproj_kernel<<<dim3(16, 8), 512, 0, stream>>>(ctx, wob, bo, out);
}

// Round 9
// 505.076 us; speedup vs baseline: 1.0441x; 1.0090x over previous
//
#include <hip/hip_runtime.h>
#include <hip/hip_bf16.h>

typedef __attribute__((ext_vector_type(8))) short short8;
typedef __attribute__((ext_vector_type(4))) ushort ushort4v;
typedef __attribute__((ext_vector_type(4))) float f32x4;

#define MFMA16(A, B, C) __builtin_amdgcn_mfma_f32_16x16x32_bf16(A, B, C, 0, 0, 0)

#define GLOAD16(gp, lp)                                        \
  __builtin_amdgcn_global_load_lds(                            \
      (__attribute__((address_space(1))) void*)(gp),           \
      (__attribute__((address_space(3))) void*)(lp), 16, 0, 0)

// Raw barrier/waitcnt (NOT __syncthreads: that drains vmcnt).
#define SBAR()   asm volatile("s_barrier" ::: "memory")
#define VMCNT6() asm volatile("s_waitcnt vmcnt(6)" ::: "memory")

static constexpr int Lx = 2048, Dx = 2048, Hx = 16, HDx = 128, NBx = 2;

__device__ __forceinline__ ushort f2bu(float f) {
  __hip_bfloat16 h = __float2bfloat16(f);
  union { __hip_bfloat16 h; ushort u; } v;
  v.h = h;
  return v.u;
}

__device__ __forceinline__ short8 pack8(const float4& a, const float4& b) {
  short8 r;
  r[0] = (short)f2bu(a.x); r[1] = (short)f2bu(a.y);
  r[2] = (short)f2bu(a.z); r[3] = (short)f2bu(a.w);
  r[4] = (short)f2bu(b.x); r[5] = (short)f2bu(b.y);
  r[6] = (short)f2bu(b.z); r[7] = (short)f2bu(b.w);
  return r;
}

// ---------------------------------------------------------------------------
// One-time f32 -> bf16 conversion of x and the 4 weight matrices.
// ---------------------------------------------------------------------------
__global__ void convert_kernel(const float* __restrict__ x,
                               const float* __restrict__ Wq,
                               const float* __restrict__ Wk,
                               const float* __restrict__ Wv,
                               const float* __restrict__ Wo,
                               ushort* __restrict__ xb, ushort* __restrict__ wqb,
                               ushort* __restrict__ wkb, ushort* __restrict__ wvb,
                               ushort* __restrict__ wob) {
  const int y = blockIdx.y;
  const float* s;
  ushort* d;
  int n;
  switch (y) {
    case 0: s = x;  d = xb;  n = NBx * Lx * Dx; break;
    case 1: s = Wq; d = wqb; n = Dx * Dx; break;
    case 2: s = Wk; d = wkb; n = Dx * Dx; break;
    case 3: s = Wv; d = wvb; n = Dx * Dx; break;
    default: s = Wo; d = wob; n = Dx * Dx; break;
  }
  const int stride = gridDim.x * blockDim.x * 8;
  for (int i = (blockIdx.x * blockDim.x + threadIdx.x) * 8; i < n; i += stride) {
    float4 a = *(const float4*)(s + i);
    float4 b = *(const float4*)(s + i + 4);
    *(short8*)(d + i) = pack8(a, b);
  }
}

// ---------------------------------------------------------------------------
// 256x256x(BK=64) GEMM core, 4 phases/K-tile, ONE barrier per phase (R9).
// R8 post-mortem: the {SBAR; lgkmcnt(0); MFMA; SBAR} phase serialized LDS
// bursts against MFMA bursts (memory-clobbered asm forbids overlap; lockstep
// waves give no TLP) -> 20% MfmaUtil. R9: each phase = {ds_reads, stage,
// MFMA cluster, SBAR}. Compiler inserts fine-grained lgkmcnt before each
// MFMA use (m97-verified behavior) -> reads overlap MFMA within a phase and
// across drifting waves. Correctness: every read is consumed by an MFMA in
// its phase, so reads complete before the wave passes the phase-end barrier;
// each stage targets a region whose last readers passed the previous
// barrier. VMCNT6 once per tile, BEFORE its barrier (cross-wave visibility
// of global_load_lds data); never drained to 0. T2 swizzle retained:
// slot' = slot ^ ((row>>1)&3), linear LDS dest + inverse-swizzled global
// source + swizzled read (conflicts measured 0 in R8).
// ---------------------------------------------------------------------------
__device__ __forceinline__ void gemm256_core(const ushort* __restrict__ A0,
                                             const ushort* __restrict__ B0,
                                             f32x4 (&acc)[8][4], const int tid) {
  __shared__ ushort LA[2][2][8192];  // [slot][kk][row*32+col], 64KB
  __shared__ ushort LB[2][2][8192];  // 64KB

  const int lane = tid & 63;
  const int l15 = lane & 15, hi = (lane >> 4) & 3;
  const int w = tid >> 6, wr = w >> 2, wc = w & 3;
  constexpr int NT = 2048 / 64;

  // swizzled read slot offset (elems): per-lane constant
  const int hs = (hi ^ ((l15 >> 1) & 3)) * 8;

  // staging: thread t -> LDS row tid>>2 (+128 for 2nd gload), slot tid&3;
  // source column inverse-swizzled so swizzled data lands at linear dest.
  const int srcSlot = ((tid & 3) ^ ((tid >> 3) & 3)) * 8;
  const ushort* aRow = A0 + (size_t)(tid >> 2) * Dx + srcSlot;
  const ushort* bRow = B0 + (size_t)(tid >> 2) * Dx + srcSlot;
  const int ldsT = (tid >> 2) * 32 + (tid & 3) * 8;  // linear: tid*16 bytes

#define STG_A(s, kk, t)                                                     \
  do {                                                                      \
    GLOAD16(aRow + (t) * 64 + (kk) * 32, &LA[s][kk][ldsT]);                 \
    GLOAD16(aRow + (size_t)128 * Dx + (t) * 64 + (kk) * 32,                 \
            &LA[s][kk][4096 + ldsT]);                                       \
  } while (0)
#define STG_B(s, kk, t)                                                     \
  do {                                                                      \
    GLOAD16(bRow + (t) * 64 + (kk) * 32, &LB[s][kk][ldsT]);                 \
    GLOAD16(bRow + (size_t)128 * Dx + (t) * 64 + (kk) * 32,                 \
            &LB[s][kk][4096 + ldsT]);                                       \
  } while (0)

#pragma unroll
  for (int m = 0; m < 8; ++m)
#pragma unroll
    for (int n = 0; n < 4; ++n) acc[m][n] = {0.f, 0.f, 0.f, 0.f};

  // prologue: tile0 complete + 3 halves of tile1 (A-kk1(1) comes at t=0.q1)
  STG_B(0, 0, 0); STG_A(0, 0, 0); STG_B(0, 1, 0); STG_A(0, 1, 0);
  STG_B(1, 0, 1); STG_A(1, 0, 1); STG_B(1, 1, 1);
  VMCNT6();  // tile0's 8 loads landed; 6 (tile1) still in flight
  SBAR();

  const int ar0 = wr * 128 + l15;
  const int br0 = wc * 64 + l15;

  for (int t = 0; t < NT; ++t) {
    const int s = t & 1;
    short8 af[4], bf[4], ag[4];

    // ---- q1: kk0, m0-3 ----
#pragma unroll
    for (int m = 0; m < 4; ++m)
      af[m] = *(const short8*)&LA[s][0][(ar0 + m * 16) * 32 + hs];
#pragma unroll
    for (int n = 0; n < 4; ++n)
      bf[n] = *(const short8*)&LB[s][0][(br0 + n * 16) * 32 + hs];
    if (t + 1 < NT) STG_A(s ^ 1, 1, t + 1);
    __builtin_amdgcn_s_setprio(1);
#pragma unroll
    for (int m = 0; m < 4; ++m)
#pragma unroll
      for (int n = 0; n < 4; ++n) acc[m][n] = MFMA16(af[m], bf[n], acc[m][n]);
    __builtin_amdgcn_s_setprio(0);
    SBAR();

    // ---- q2: kk0, m4-7 (reuse bf) ----
#pragma unroll
    for (int m = 0; m < 4; ++m)
      ag[m] = *(const short8*)&LA[s][0][(ar0 + (m + 4) * 16) * 32 + hs];
    if (t + 2 < NT) STG_B(s, 0, t + 2);
    __builtin_amdgcn_s_setprio(1);
#pragma unroll
    for (int m = 0; m < 4; ++m)
#pragma unroll
      for (int n = 0; n < 4; ++n)
        acc[m + 4][n] = MFMA16(ag[m], bf[n], acc[m + 4][n]);
    __builtin_amdgcn_s_setprio(0);
    SBAR();

    // ---- q3: kk1, m0-3 ----
#pragma unroll
    for (int m = 0; m < 4; ++m)
      af[m] = *(const short8*)&LA[s][1][(ar0 + m * 16) * 32 + hs];
#pragma unroll
    for (int n = 0; n < 4; ++n)
      bf[n] = *(const short8*)&LB[s][1][(br0 + n * 16) * 32 + hs];
    if (t + 2 < NT) STG_A(s, 0, t + 2);
    __builtin_amdgcn_s_setprio(1);
#pragma unroll
    for (int m = 0; m < 4; ++m)
#pragma unroll
      for (int n = 0; n < 4; ++n) acc[m][n] = MFMA16(af[m], bf[n], acc[m][n]);
    __builtin_amdgcn_s_setprio(0);
    SBAR();

    // ---- q4: kk1, m4-7 (reuse bf) ----
#pragma unroll
    for (int m = 0; m < 4; ++m)
      ag[m] = *(const short8*)&LA[s][1][(ar0 + (m + 4) * 16) * 32 + hs];
    if (t + 2 < NT) STG_B(s, 1, t + 2);
    __builtin_amdgcn_s_setprio(1);
#pragma unroll
    for (int m = 0; m < 4; ++m)
#pragma unroll
      for (int n = 0; n < 4; ++n)
        acc[m + 4][n] = MFMA16(ag[m], bf[n], acc[m + 4][n]);
    __builtin_amdgcn_s_setprio(0);
    VMCNT6();  // tile t+1 fully landed before next q1's reads; never 0
    SBAR();
  }
#undef STG_A
#undef STG_B
}

// ---------------------------------------------------------------------------
// QKV projection: one 8-phase GEMM over concatenated [Wq;Wk;Wv] (6144x2048).
// ---------------------------------------------------------------------------
__global__ __launch_bounds__(512, 2) void qkv_kernel(
    const ushort* __restrict__ xb, const ushort* __restrict__ Wall,
    const float* __restrict__ bq, const float* __restrict__ bk,
    const float* __restrict__ bv,
    const float* __restrict__ sinT, const float* __restrict__ cosT,
    ushort* __restrict__ qw, ushort* __restrict__ kw, ushort* __restrict__ vw) {
  const int bm = blockIdx.x;   // 0..15
  const int bnp = blockIdx.y;  // 0..23
  const int z = bnp >> 3, bn = bnp & 7;
  const int tid = threadIdx.x;

  f32x4 acc[8][4];
  gemm256_core(xb + (size_t)bm * 256 * Dx, Wall + (size_t)bnp * 256 * Dx, acc, tid);

  const float* bias = (z == 0) ? bq : (z == 1) ? bk : bv;
  ushort* outp      = (z == 0) ? qw : (z == 1) ? kw : vw;
  const int lane = tid & 63, l15 = lane & 15, hi = (lane >> 4) & 3;
  const int w = tid >> 6, wr = w >> 2, wc = w & 3;
  const float rsHD = 0.08838834764831845f;  // 1/sqrt(128)
#pragma unroll
  for (int n = 0; n < 4; ++n) {
    const int nc = bn * 256 + wc * 64 + n * 16 + l15;  // 0..2047
    const int h = nc >> 7, d = nc & 127;
    const float bb = bias[nc];
#pragma unroll
    for (int m = 0; m < 8; ++m) {
#pragma unroll
      for (int r = 0; r < 4; ++r) {
        const int mg = bm * 256 + wr * 128 + m * 16 + hi * 4 + r;
        const int b = mg >> 11, l = mg & (Lx - 1);
        float v = acc[m][n][r] + bb;
        if (z < 2 && d < 64) v *= (cosT[l * 64 + d] - sinT[l * 64 + d]);
        if (z == 0) v *= rsHD;
        outp[(size_t)((b * Hx + h) * Lx + l) * HDx + d] = f2bu(v);
      }
    }
  }
}

// ---------------------------------------------------------------------------
// Output projection: same core; f32 out + bias. grid (16, 8).
// ---------------------------------------------------------------------------
__global__ __launch_bounds__(512, 2) void oproj_kernel(
    const ushort* __restrict__ ctx, const ushort* __restrict__ wob,
    const float* __restrict__ bo, float* __restrict__ out) {
  const int bm = blockIdx.x;  // 0..15
  const int bn = blockIdx.y;  // 0..7
  const int tid = threadIdx.x;

  f32x4 acc[8][4];
  gemm256_core(ctx + (size_t)bm * 256 * Dx, wob + (size_t)bn * 256 * Dx, acc, tid);

  const int lane = tid & 63, l15 = lane & 15, hi = (lane >> 4) & 3;
  const int w = tid >> 6, wr = w >> 2, wc = w & 3;
#pragma unroll
  for (int n = 0; n < 4; ++n) {
    const int nc = bn * 256 + wc * 64 + n * 16 + l15;
    const float bb = bo[nc];
#pragma unroll
    for (int m = 0; m < 8; ++m) {
#pragma unroll
      for (int r = 0; r < 4; ++r) {
        const int mg = bm * 256 + wr * 128 + m * 16 + hi * 4 + r;
        out[(size_t)mg * Dx + nc] = acc[m][n][r] + bb;
      }
    }
  }
}

// ---------------------------------------------------------------------------
// Causal flash attention (unchanged from R5/R8).
// ---------------------------------------------------------------------------
__global__ __launch_bounds__(256, 2) void attn_kernel(
    const ushort* __restrict__ qw, const ushort* __restrict__ kw,
    const ushort* __restrict__ vw, ushort* __restrict__ ctx) {
  const int pair = blockIdx.x;  // 0..15
  const int bh = blockIdx.y;
  const int b = bh >> 4, h = bh & 15;
  const int tid = threadIdx.x;
  const int w = tid >> 6, l15 = tid & 15, hi = (tid >> 4) & 3;

  const ushort* Q = qw + (size_t)bh * Lx * HDx;
  const ushort* K = kw + (size_t)bh * Lx * HDx;
  const ushort* V = vw + (size_t)bh * Lx * HDx;

  __shared__ ushort Ks[64][136];
  __shared__ ushort Vt[128][76];
  __shared__ ushort Ps[4][16][76];

  const int skrow = tid >> 2, skd = (tid & 3) * 32;
  const int svk = (tid & 15) * 4, svd = (tid >> 4) * 8;

  for (int seg = 0; seg < 2; ++seg) {
    const int qt = seg ? (31 - pair) : pair;

    short8 qf[4];
    {
      const ushort* qr = Q + (size_t)(qt * 64 + w * 16 + l15) * HDx + hi * 8;
#pragma unroll
      for (int ds = 0; ds < 4; ++ds) qf[ds] = *(const short8*)(qr + ds * 32);
    }

    f32x4 o[8];
#pragma unroll
    for (int df = 0; df < 8; ++df) o[df] = {0.f, 0.f, 0.f, 0.f};
    float mr[4], lr[4];
#pragma unroll
    for (int r = 0; r < 4; ++r) { mr[r] = -1e30f; lr[r] = 0.f; }

    short8 kreg[4], vreg[4];
    {
      const ushort* kp = K + (size_t)skrow * HDx + skd;
      kreg[0] = *(const short8*)(kp + 0);  kreg[1] = *(const short8*)(kp + 8);
      kreg[2] = *(const short8*)(kp + 16); kreg[3] = *(const short8*)(kp + 24);
      const ushort* vp = V + (size_t)svk * HDx + svd;
      vreg[0] = *(const short8*)(vp);
      vreg[1] = *(const short8*)(vp + HDx);
      vreg[2] = *(const short8*)(vp + 2 * HDx);
      vreg[3] = *(const short8*)(vp + 3 * HDx);
    }

    for (int kv = 0; kv <= qt; ++kv) {
      __syncthreads();
      *(short8*)&Ks[skrow][skd + 0] = kreg[0];
      *(short8*)&Ks[skrow][skd + 8] = kreg[1];
      *(short8*)&Ks[skrow][skd + 16] = kreg[2];
      *(short8*)&Ks[skrow][skd + 24] = kreg[3];
#pragma unroll
      for (int j = 0; j < 8; ++j) {
        ushort4v pk;
        pk[0] = (ushort)vreg[0][j]; pk[1] = (ushort)vreg[1][j];
        pk[2] = (ushort)vreg[2][j]; pk[3] = (ushort)vreg[3][j];
        *(ushort4v*)&Vt[svd + j][svk] = pk;
      }
      __syncthreads();

      if (kv < qt) {
        const ushort* kp = K + (size_t)((kv + 1) * 64 + skrow) * HDx + skd;
        kreg[0] = *(const short8*)(kp + 0);  kreg[1] = *(const short8*)(kp + 8);
        kreg[2] = *(const short8*)(kp + 16); kreg[3] = *(const short8*)(kp + 24);
        const ushort* vp = V + (size_t)((kv + 1) * 64 + svk) * HDx + svd;
        vreg[0] = *(const short8*)(vp);
        vreg[1] = *(const short8*)(vp + HDx);
        vreg[2] = *(const short8*)(vp + 2 * HDx);
        vreg[3] = *(const short8*)(vp + 3 * HDx);
      }

      f32x4 s[4];
#pragma unroll
      for (int kf = 0; kf < 4; ++kf) s[kf] = {0.f, 0.f, 0.f, 0.f};
      __builtin_amdgcn_s_setprio(1);
#pragma unroll
      for (int kf = 0; kf < 4; ++kf)
#pragma unroll
        for (int ds = 0; ds < 4; ++ds) {
          short8 kb = *(const short8*)&Ks[kf * 16 + l15][ds * 32 + hi * 8];
          s[kf] = MFMA16(qf[ds], kb, s[kf]);
        }
      __builtin_amdgcn_s_setprio(0);

      if (kv == qt) {
#pragma unroll
        for (int kf = 0; kf < 4; ++kf)
#pragma unroll
          for (int r = 0; r < 4; ++r)
            if (kf * 16 + l15 > w * 16 + hi * 4 + r) s[kf][r] = -1e30f;
      }

      float ml[4];
#pragma unroll
      for (int r = 0; r < 4; ++r)
        ml[r] = fmaxf(fmaxf(s[0][r], s[1][r]), fmaxf(s[2][r], s[3][r]));
#pragma unroll
      for (int off = 1; off <= 8; off <<= 1)
#pragma unroll
        for (int r = 0; r < 4; ++r) ml[r] = fmaxf(ml[r], __shfl_xor(ml[r], off));
      float scl[4];
#pragma unroll
      for (int r = 0; r < 4; ++r) {
        float mn = fmaxf(mr[r], ml[r]);
        scl[r] = __expf(mr[r] - mn);
        mr[r] = mn;
      }
      float ll[4] = {0.f, 0.f, 0.f, 0.f};
#pragma unroll
      for (int kf = 0; kf < 4; ++kf)
#pragma unroll
        for (int r = 0; r < 4; ++r) {
          float p = __expf(s[kf][r] - mr[r]);
          s[kf][r] = p;
          ll[r] += p;
        }
#pragma unroll
      for (int off = 1; off <= 8; off <<= 1)
#pragma unroll
        for (int r = 0; r < 4; ++r) ll[r] += __shfl_xor(ll[r], off);
#pragma unroll
      for (int r = 0; r < 4; ++r) lr[r] = lr[r] * scl[r] + ll[r];
#pragma unroll
      for (int df = 0; df < 8; ++df)
#pragma unroll
        for (int r = 0; r < 4; ++r) o[df][r] *= scl[r];

#pragma unroll
      for (int kf = 0; kf < 4; ++kf)
#pragma unroll
        for (int r = 0; r < 4; ++r)
          Ps[w][hi * 4 + r][kf * 16 + l15] = f2bu(s[kf][r]);

      short8 pa0 = *(const short8*)&Ps[w][l15][hi * 8];
      short8 pa1 = *(const short8*)&Ps[w][l15][32 + hi * 8];
      __builtin_amdgcn_s_setprio(1);
#pragma unroll
      for (int df = 0; df < 8; ++df) {
        short8 v0 = *(const short8*)&Vt[df * 16 + l15][hi * 8];
        short8 v1 = *(const short8*)&Vt[df * 16 + l15][32 + hi * 8];
        o[df] = MFMA16(pa0, v0, o[df]);
        o[df] = MFMA16(pa1, v1, o[df]);
      }
      __builtin_amdgcn_s_setprio(0);
    }

    float inv[4];
#pragma unroll
    for (int r = 0; r < 4; ++r) inv[r] = 1.0f / lr[r];
    ushort* cp = ctx + (size_t)(b * Lx + qt * 64 + w * 16) * Dx + h * HDx;
#pragma unroll
    for (int df = 0; df < 8; ++df)
#pragma unroll
      for (int r = 0; r < 4; ++r)
        cp[(size_t)(hi * 4 + r) * Dx + df * 16 + l15] = f2bu(o[df][r] * inv[r]);
  }
}

extern "C" void kernel_launch(void* const* d_in, const int* in_sizes, int n_in,
                              void* d_out, int out_size, void* d_ws, size_t ws_size,
                              hipStream_t stream) {
  (void)in_sizes; (void)n_in; (void)out_size; (void)ws_size;
  const float* x    = (const float*)d_in[0];
  const float* sinT = (const float*)d_in[1];
  const float* cosT = (const float*)d_in[2];
  // d_in[3] = mask (causal tril) — enforced analytically in attn_kernel
  const float* Wq = (const float*)d_in[4];
  const float* bq = (const float*)d_in[5];
  const float* Wk = (const float*)d_in[6];
  const float* bk = (const float*)d_in[7];
  const float* Wv = (const float*)d_in[8];
  const float* bv = (const float*)d_in[9];
  const float* Wo = (const float*)d_in[10];
  const float* bo = (const float*)d_in[11];
  float* out = (float*)d_out;

  const size_t N = (size_t)NBx * Lx * Dx;  // 8,388,608
  const size_t M = (size_t)Dx * Dx;        // 4,194,304
  ushort* qw  = (ushort*)d_ws;
  ushort* kw  = qw + N;
  ushort* vw  = kw + N;
  ushort* ctx = vw + N;
  ushort* xb  = ctx;  // alias: xb consumed by qkv before attn writes ctx
  ushort* wqb = ctx + N;  // wqb/wkb/wvb contiguous -> [Wq;Wk;Wv] (6144x2048)
  ushort* wkb = wqb + M;
  ushort* wvb = wkb + M;
  ushort* wob = wvb + M;
  (void)wkb; (void)wvb;

  convert_kernel<<<dim3(1024, 5), 256, 0, stream>>>(
      x, Wq, Wk, Wv, Wo, xb, wqb, wkb, wvb, wob);
  qkv_kernel<<<dim3(16, 24), 512, 0, stream>>>(
      xb, wqb, bq, bk, bv, sinT, cosT, qw, kw, vw);
  attn_kernel<<<dim3(16, 32), 256, 0, stream>>>(qw, kw, vw, ctx);
  oproj_kernel<<<dim3(16, 8), 512, 0, stream>>>(ctx, wob, bo, out);
}

// Round 11
// 454.866 us; speedup vs baseline: 1.1593x; 1.1104x over previous
//
#include <hip/hip_runtime.h>
#include <hip/hip_bf16.h>

typedef __attribute__((ext_vector_type(8))) short short8;
typedef __attribute__((ext_vector_type(4))) ushort ushort4v;
typedef __attribute__((ext_vector_type(4))) float f32x4;

#define MFMA16(A, B, C) __builtin_amdgcn_mfma_f32_16x16x32_bf16(A, B, C, 0, 0, 0)

#define GLOAD16(gp, lp)                                        \
  __builtin_amdgcn_global_load_lds(                            \
      (__attribute__((address_space(1))) void*)(gp),           \
      (__attribute__((address_space(3))) void*)(lp), 16, 0, 0)

static constexpr int Lx = 2048, Dx = 2048, Hx = 16, HDx = 128, NBx = 2;

__device__ __forceinline__ ushort f2bu(float f) {
  __hip_bfloat16 h = __float2bfloat16(f);
  union { __hip_bfloat16 h; ushort u; } v;
  v.h = h;
  return v.u;
}

__device__ __forceinline__ short8 pack8(const float4& a, const float4& b) {
  short8 r;
  r[0] = (short)f2bu(a.x); r[1] = (short)f2bu(a.y);
  r[2] = (short)f2bu(a.z); r[3] = (short)f2bu(a.w);
  r[4] = (short)f2bu(b.x); r[5] = (short)f2bu(b.y);
  r[6] = (short)f2bu(b.z); r[7] = (short)f2bu(b.w);
  return r;
}

// ---------------------------------------------------------------------------
// One-time f32 -> bf16 conversion of x and the 4 weight matrices.
// ---------------------------------------------------------------------------
__global__ void convert_kernel(const float* __restrict__ x,
                               const float* __restrict__ Wq,
                               const float* __restrict__ Wk,
                               const float* __restrict__ Wv,
                               const float* __restrict__ Wo,
                               ushort* __restrict__ xb, ushort* __restrict__ wqb,
                               ushort* __restrict__ wkb, ushort* __restrict__ wvb,
                               ushort* __restrict__ wob) {
  const int y = blockIdx.y;
  const float* s;
  ushort* d;
  int n;
  switch (y) {
    case 0: s = x;  d = xb;  n = NBx * Lx * Dx; break;
    case 1: s = Wq; d = wqb; n = Dx * Dx; break;
    case 2: s = Wk; d = wkb; n = Dx * Dx; break;
    case 3: s = Wv; d = wvb; n = Dx * Dx; break;
    default: s = Wo; d = wob; n = Dx * Dx; break;
  }
  const int stride = gridDim.x * blockDim.x * 8;
  for (int i = (blockIdx.x * blockDim.x + threadIdx.x) * 8; i < n; i += stride) {
    float4 a = *(const float4*)(s + i);
    float4 b = *(const float4*)(s + i + 4);
    *(short8*)(d + i) = pack8(a, b);
  }
}

// ---------------------------------------------------------------------------
// QKV projection — R5-measured m97 structure (165us, 27% MfmaUtil, ~2.6
// blocks/CU implicit overlap). 128x128 tile, BK=32, 4 waves, global_load_lds
// width-16 staging, double-buffered, 1 barrier/K-step.
// ---------------------------------------------------------------------------
__global__ __launch_bounds__(256, 2) void qkv_kernel(
    const ushort* __restrict__ xb,
    const ushort* __restrict__ wqb, const float* __restrict__ bq,
    const ushort* __restrict__ wkb, const float* __restrict__ bk,
    const ushort* __restrict__ wvb, const float* __restrict__ bv,
    const float* __restrict__ sinT, const float* __restrict__ cosT,
    ushort* __restrict__ qw, ushort* __restrict__ kw, ushort* __restrict__ vw) {
  const int z = blockIdx.z;
  const ushort* W   = (z == 0) ? wqb : (z == 1) ? wkb : wvb;
  const float* bias = (z == 0) ? bq : (z == 1) ? bk : bv;
  ushort* outp      = (z == 0) ? qw : (z == 1) ? kw : vw;

  const int bm = blockIdx.x, bn = blockIdx.y;
  const int tid = threadIdx.x;
  const int lane = tid & 63;
  const int w = tid >> 6;
  const int l15 = tid & 15, hi = (tid >> 4) & 3;
  const int wm = (w >> 1) * 64, wn = (w & 1) * 64;

  __shared__ ushort As[2][128 * 32];
  __shared__ ushort Bs[2][128 * 32];

  const int cA = w * 2;
  const int srow = cA * 16 + (lane >> 2);
  const int scol = (lane & 3) * 8;
  const ushort* aSrc = xb + (size_t)(bm * 128 + srow) * Dx + scol;
  const ushort* bSrc = W + (size_t)(bn * 128 + srow) * Dx + scol;
  const int ldsOff = cA * 512;

#define STAGE_QKV(buf, kt)                                           \
  do {                                                               \
    const ushort* ap = aSrc + (kt) * 32;                             \
    const ushort* bp = bSrc + (kt) * 32;                             \
    GLOAD16(ap, &As[buf][ldsOff]);                                   \
    GLOAD16(ap + 16 * Dx, &As[buf][ldsOff + 512]);                   \
    GLOAD16(bp, &Bs[buf][ldsOff]);                                   \
    GLOAD16(bp + 16 * Dx, &Bs[buf][ldsOff + 512]);                   \
  } while (0)

  f32x4 acc[4][4];
#pragma unroll
  for (int i = 0; i < 4; ++i)
#pragma unroll
    for (int j = 0; j < 4; ++j) acc[i][j] = {0.f, 0.f, 0.f, 0.f};

  STAGE_QKV(0, 0);
  __syncthreads();

  int cur = 0;
  for (int kt = 0; kt < 64; ++kt) {
    if (kt < 63) STAGE_QKV(cur ^ 1, kt + 1);
    short8 af[4], bf[4];
#pragma unroll
    for (int i = 0; i < 4; ++i)
      af[i] = *(const short8*)&As[cur][(wm + i * 16 + l15) * 32 + hi * 8];
#pragma unroll
    for (int j = 0; j < 4; ++j)
      bf[j] = *(const short8*)&Bs[cur][(wn + j * 16 + l15) * 32 + hi * 8];
#pragma unroll
    for (int i = 0; i < 4; ++i)
#pragma unroll
      for (int j = 0; j < 4; ++j) acc[i][j] = MFMA16(af[i], bf[j], acc[i][j]);
    __syncthreads();
    cur ^= 1;
  }
#undef STAGE_QKV

  const float rsHD = 0.08838834764831845f;  // 1/sqrt(128)
#pragma unroll
  for (int j = 0; j < 4; ++j) {
    const int n = bn * 128 + wn + j * 16 + l15;
    const int h = n >> 7, d = n & 127;
    const float bb = bias[n];
#pragma unroll
    for (int i = 0; i < 4; ++i) {
#pragma unroll
      for (int r = 0; r < 4; ++r) {
        const int m = bm * 128 + wm + i * 16 + hi * 4 + r;
        const int b = m >> 11, l = m & (Lx - 1);
        float v = acc[i][j][r] + bb;
        if (z < 2 && d < 64) v *= (cosT[l * 64 + d] - sinT[l * 64 + d]);
        if (z == 0) v *= rsHD;
        outp[(size_t)((b * Hx + h) * Lx + l) * HDx + d] = f2bu(v);
      }
    }
  }
}

// ---------------------------------------------------------------------------
// Causal flash attention v3 (R10 experiment): QBLK=128, 8 waves, 512 thr.
// Same per-wave work as v2 (16 q-rows, frag QK/softmax/PV); each K/V tile
// now serves 128 q-rows -> staging traffic + barriers per unit work HALVED.
// Pair-balanced: block does qt=i then 15-i (34 kv-iters each). Grid 256.
// Waves 0-3 waste the 2nd diagonal tile (fully masked, ~3%) - accepted.
// ---------------------------------------------------------------------------
__global__ __launch_bounds__(512, 2) void attn_kernel(
    const ushort* __restrict__ qw, const ushort* __restrict__ kw,
    const ushort* __restrict__ vw, ushort* __restrict__ ctx) {
  const int pair = blockIdx.x;  // 0..7
  const int bh = blockIdx.y;
  const int b = bh >> 4, h = bh & 15;
  const int tid = threadIdx.x;
  const int w = tid >> 6, l15 = tid & 15, hi = (tid >> 4) & 3;

  const ushort* Q = qw + (size_t)bh * Lx * HDx;
  const ushort* K = kw + (size_t)bh * Lx * HDx;
  const ushort* V = vw + (size_t)bh * Lx * HDx;

  __shared__ ushort Ks[64][136];
  __shared__ ushort Vt[128][76];
  __shared__ ushort Ps[8][16][76];

  const int skrow = tid >> 3, skc = (tid & 7) * 16;     // K: 2 short8/thread
  const int svk = (tid & 15) * 4, svd = (tid >> 4) * 4; // V: 4x4 transpose/thread

  for (int seg = 0; seg < 2; ++seg) {
    const int qt = seg ? (15 - pair) : pair;  // 128-row q-tile index
    const int nkv = 2 * qt + 2;               // 64-wide kv tiles

    short8 qf[4];
    {
      const ushort* qr = Q + (size_t)(qt * 128 + w * 16 + l15) * HDx + hi * 8;
#pragma unroll
      for (int ds = 0; ds < 4; ++ds) qf[ds] = *(const short8*)(qr + ds * 32);
    }

    f32x4 o[8];
#pragma unroll
    for (int df = 0; df < 8; ++df) o[df] = {0.f, 0.f, 0.f, 0.f};
    float mr[4], lr[4];
#pragma unroll
    for (int r = 0; r < 4; ++r) { mr[r] = -1e30f; lr[r] = 0.f; }

    // prologue: prefetch kv=0 into regs
    short8 kreg0, kreg1;
    ushort4v vreg[4];
    {
      const ushort* kp = K + (size_t)skrow * HDx + skc;
      kreg0 = *(const short8*)(kp);
      kreg1 = *(const short8*)(kp + 8);
      const ushort* vp = V + (size_t)svk * HDx + svd;
#pragma unroll
      for (int j = 0; j < 4; ++j) vreg[j] = *(const ushort4v*)(vp + j * HDx);
    }

    for (int kv = 0; kv < nkv; ++kv) {
      __syncthreads();  // LDS free (prev tile's reads / prev segment done)
      *(short8*)&Ks[skrow][skc] = kreg0;
      *(short8*)&Ks[skrow][skc + 8] = kreg1;
#pragma unroll
      for (int i = 0; i < 4; ++i) {
        ushort4v pk;
        pk[0] = vreg[0][i]; pk[1] = vreg[1][i];
        pk[2] = vreg[2][i]; pk[3] = vreg[3][i];
        *(ushort4v*)&Vt[svd + i][svk] = pk;
      }
      __syncthreads();

      if (kv + 1 < nkv) {  // issue next tile's loads early
        const ushort* kp = K + (size_t)((kv + 1) * 64 + skrow) * HDx + skc;
        kreg0 = *(const short8*)(kp);
        kreg1 = *(const short8*)(kp + 8);
        const ushort* vp = V + (size_t)((kv + 1) * 64 + svk) * HDx + svd;
#pragma unroll
        for (int j = 0; j < 4; ++j) vreg[j] = *(const ushort4v*)(vp + j * HDx);
      }

      // S = Q K^T
      f32x4 s[4];
#pragma unroll
      for (int kf = 0; kf < 4; ++kf) s[kf] = {0.f, 0.f, 0.f, 0.f};
      __builtin_amdgcn_s_setprio(1);
#pragma unroll
      for (int kf = 0; kf < 4; ++kf)
#pragma unroll
        for (int ds = 0; ds < 4; ++ds) {
          short8 kb = *(const short8*)&Ks[kf * 16 + l15][ds * 32 + hi * 8];
          s[kf] = MFMA16(qf[ds], kb, s[kf]);
        }
      __builtin_amdgcn_s_setprio(0);

      if (kv >= 2 * qt) {  // diagonal tiles: causal mask (tile-relative)
        const int coff = (kv - 2 * qt) * 64;
#pragma unroll
        for (int kf = 0; kf < 4; ++kf)
#pragma unroll
          for (int r = 0; r < 4; ++r)
            if (coff + kf * 16 + l15 > w * 16 + hi * 4 + r) s[kf][r] = -1e30f;
      }

      // online softmax
      float ml[4];
#pragma unroll
      for (int r = 0; r < 4; ++r)
        ml[r] = fmaxf(fmaxf(s[0][r], s[1][r]), fmaxf(s[2][r], s[3][r]));
#pragma unroll
      for (int off = 1; off <= 8; off <<= 1)
#pragma unroll
        for (int r = 0; r < 4; ++r) ml[r] = fmaxf(ml[r], __shfl_xor(ml[r], off));
      float scl[4];
#pragma unroll
      for (int r = 0; r < 4; ++r) {
        float mn = fmaxf(mr[r], ml[r]);
        scl[r] = __expf(mr[r] - mn);
        mr[r] = mn;
      }
      float ll[4] = {0.f, 0.f, 0.f, 0.f};
#pragma unroll
      for (int kf = 0; kf < 4; ++kf)
#pragma unroll
        for (int r = 0; r < 4; ++r) {
          float p = __expf(s[kf][r] - mr[r]);
          s[kf][r] = p;
          ll[r] += p;
        }
#pragma unroll
      for (int off = 1; off <= 8; off <<= 1)
#pragma unroll
        for (int r = 0; r < 4; ++r) ll[r] += __shfl_xor(ll[r], off);
#pragma unroll
      for (int r = 0; r < 4; ++r) lr[r] = lr[r] * scl[r] + ll[r];
#pragma unroll
      for (int df = 0; df < 8; ++df)
#pragma unroll
        for (int r = 0; r < 4; ++r) o[df][r] *= scl[r];

      // P -> per-wave LDS (C-layout -> A-layout)
#pragma unroll
      for (int kf = 0; kf < 4; ++kf)
#pragma unroll
        for (int r = 0; r < 4; ++r)
          Ps[w][hi * 4 + r][kf * 16 + l15] = f2bu(s[kf][r]);

      short8 pa0 = *(const short8*)&Ps[w][l15][hi * 8];
      short8 pa1 = *(const short8*)&Ps[w][l15][32 + hi * 8];
      __builtin_amdgcn_s_setprio(1);
#pragma unroll
      for (int df = 0; df < 8; ++df) {
        short8 v0 = *(const short8*)&Vt[df * 16 + l15][hi * 8];
        short8 v1 = *(const short8*)&Vt[df * 16 + l15][32 + hi * 8];
        o[df] = MFMA16(pa0, v0, o[df]);
        o[df] = MFMA16(pa1, v1, o[df]);
      }
      __builtin_amdgcn_s_setprio(0);
    }

    // epilogue for this segment
    float inv[4];
#pragma unroll
    for (int r = 0; r < 4; ++r) inv[r] = 1.0f / lr[r];
    ushort* cp = ctx + (size_t)(b * Lx + qt * 128 + w * 16) * Dx + h * HDx;
#pragma unroll
    for (int df = 0; df < 8; ++df)
#pragma unroll
      for (int r = 0; r < 4; ++r)
        cp[(size_t)(hi * 4 + r) * Dx + df * 16 + l15] = f2bu(o[df][r] * inv[r]);
  }
}

// ---------------------------------------------------------------------------
// Output projection — R5-measured m97 structure.
// ---------------------------------------------------------------------------
__global__ __launch_bounds__(256, 2) void oproj_kernel(
    const ushort* __restrict__ ctx, const ushort* __restrict__ wob,
    const float* __restrict__ bo, float* __restrict__ out) {
  const int bm = blockIdx.x, bn = blockIdx.y;
  const int tid = threadIdx.x;
  const int lane = tid & 63;
  const int w = tid >> 6;
  const int l15 = tid & 15, hi = (tid >> 4) & 3;
  const int wm = (w >> 1) * 64, wn = (w & 1) * 64;

  __shared__ ushort As[2][128 * 32];
  __shared__ ushort Bs[2][128 * 32];

  const int cA = w * 2;
  const int srow = cA * 16 + (lane >> 2);
  const int scol = (lane & 3) * 8;
  const ushort* aSrc = ctx + (size_t)(bm * 128 + srow) * Dx + scol;
  const ushort* bSrc = wob + (size_t)(bn * 128 + srow) * Dx + scol;
  const int ldsOff = cA * 512;

#define STAGE_O(buf, kt)                                             \
  do {                                                               \
    const ushort* ap = aSrc + (kt) * 32;                             \
    const ushort* bp = bSrc + (kt) * 32;                             \
    GLOAD16(ap, &As[buf][ldsOff]);                                   \
    GLOAD16(ap + 16 * Dx, &As[buf][ldsOff + 512]);                   \
    GLOAD16(bp, &Bs[buf][ldsOff]);                                   \
    GLOAD16(bp + 16 * Dx, &Bs[buf][ldsOff + 512]);                   \
  } while (0)

  f32x4 acc[4][4];
#pragma unroll
  for (int i = 0; i < 4; ++i)
#pragma unroll
    for (int j = 0; j < 4; ++j) acc[i][j] = {0.f, 0.f, 0.f, 0.f};

  STAGE_O(0, 0);
  __syncthreads();

  int cur = 0;
  for (int kt = 0; kt < 64; ++kt) {
    if (kt < 63) STAGE_O(cur ^ 1, kt + 1);
    short8 af[4], bf[4];
#pragma unroll
    for (int i = 0; i < 4; ++i)
      af[i] = *(const short8*)&As[cur][(wm + i * 16 + l15) * 32 + hi * 8];
#pragma unroll
    for (int j = 0; j < 4; ++j)
      bf[j] = *(const short8*)&Bs[cur][(wn + j * 16 + l15) * 32 + hi * 8];
#pragma unroll
    for (int i = 0; i < 4; ++i)
#pragma unroll
      for (int j = 0; j < 4; ++j) acc[i][j] = MFMA16(af[i], bf[j], acc[i][j]);
    __syncthreads();
    cur ^= 1;
  }
#undef STAGE_O

#pragma unroll
  for (int j = 0; j < 4; ++j) {
    const int n = bn * 128 + wn + j * 16 + l15;
    const float bb = bo[n];
#pragma unroll
    for (int i = 0; i < 4; ++i)
#pragma unroll
      for (int r = 0; r < 4; ++r) {
        const int m = bm * 128 + wm + i * 16 + hi * 4 + r;
        out[(size_t)m * Dx + n] = acc[i][j][r] + bb;
      }
  }
}

extern "C" void kernel_launch(void* const* d_in, const int* in_sizes, int n_in,
                              void* d_out, int out_size, void* d_ws, size_t ws_size,
                              hipStream_t stream) {
  (void)in_sizes; (void)n_in; (void)out_size; (void)ws_size;
  const float* x    = (const float*)d_in[0];
  const float* sinT = (const float*)d_in[1];
  const float* cosT = (const float*)d_in[2];
  // d_in[3] = mask (causal tril) — enforced analytically in attn_kernel
  const float* Wq = (const float*)d_in[4];
  const float* bq = (const float*)d_in[5];
  const float* Wk = (const float*)d_in[6];
  const float* bk = (const float*)d_in[7];
  const float* Wv = (const float*)d_in[8];
  const float* bv = (const float*)d_in[9];
  const float* Wo = (const float*)d_in[10];
  const float* bo = (const float*)d_in[11];
  float* out = (float*)d_out;

  const size_t N = (size_t)NBx * Lx * Dx;  // 8,388,608
  const size_t M = (size_t)Dx * Dx;        // 4,194,304
  ushort* qw  = (ushort*)d_ws;
  ushort* kw  = qw + N;
  ushort* vw  = kw + N;
  ushort* ctx = vw + N;
  ushort* xb  = ctx;  // alias: xb consumed by qkv before attn writes ctx
  ushort* wqb = ctx + N;
  ushort* wkb = wqb + M;
  ushort* wvb = wkb + M;
  ushort* wob = wvb + M;

  convert_kernel<<<dim3(1024, 5), 256, 0, stream>>>(
      x, Wq, Wk, Wv, Wo, xb, wqb, wkb, wvb, wob);
  qkv_kernel<<<dim3(32, 16, 3), 256, 0, stream>>>(
      xb, wqb, bq, wkb, bk, wvb, bv, sinT, cosT, qw, kw, vw);
  attn_kernel<<<dim3(8, 32), 512, 0, stream>>>(qw, kw, vw, ctx);
  oproj_kernel<<<dim3(32, 16), 256, 0, stream>>>(ctx, wob, bo, out);
}